// Round 1
// baseline (1020.155 us; speedup 1.0000x reference)
//
#include <hip/hip_runtime.h>
#include <hip/hip_bf16.h>

// Problem constants
#define NROWS 65536      // 64*32*32
#define DIM   256
#define NCODE 1024
#define OUT_ELEMS 16777216  // NROWS*DIM

// K1 tiling
#define MT   32     // rows per block
#define CCH  128    // codes per outer chunk
#define DCH  64     // d per inner chunk
#define EPAD 68     // padded word stride for e_sub (64 + 4, keeps 16B align, 4-way max conflict)

// ---------------------------------------------------------------------------
// K0: per-code squared norms se[c] = sum_d e[c][d]^2
// ---------------------------------------------------------------------------
__global__ void k_se(const float* __restrict__ e, float* __restrict__ se) {
    int c = blockIdx.x * blockDim.x + threadIdx.x;
    if (c < NCODE) {
        const float4* r = (const float4*)(e + (size_t)c * DIM);
        float s = 0.f;
        #pragma unroll
        for (int i = 0; i < DIM / 4; ++i) {
            float4 v = r[i];
            s += v.x * v.x + v.y * v.y + v.z * v.z + v.w * v.w;
        }
        se[c] = s;
    }
}

// ---------------------------------------------------------------------------
// K1: fused distance + argmin.  score(n,k) = se[k] - 2*dot(x_n, e_k)
// Block: 256 threads, 32 rows. Thread (rg = t>>5 in 0..7, cg = t&31):
//   rows rg*4..rg*4+3, codes (per chunk) cg + 32*j, j=0..3.
// x tile (32x256 f32 = 32KB) persistent in LDS; e staged 128 codes x 64 d.
// ---------------------------------------------------------------------------
__global__ __launch_bounds__(256, 2)
void k_argmin(const float* __restrict__ x, const float* __restrict__ e,
              const float* __restrict__ se, int* __restrict__ idx_out) {
    __shared__ float xs[MT * DIM];        // 32 KB
    __shared__ float es[CCH * EPAD];      // 34.8 KB

    const int t  = threadIdx.x;
    const int rg = t >> 5;                // 0..7
    const int cg = t & 31;                // 0..31
    const int row0 = blockIdx.x * MT;

    // stage x tile: 8192 floats = 2048 float4, 8 per thread, coalesced
    {
        const float4* src = (const float4*)(x + (size_t)row0 * DIM);
        float4* dst = (float4*)xs;
        #pragma unroll
        for (int i = 0; i < 8; ++i) dst[t + 256 * i] = src[t + 256 * i];
    }
    __syncthreads();

    float best[4];
    int   bi[4];
    #pragma unroll
    for (int i = 0; i < 4; ++i) { best[i] = 3.0e38f; bi[i] = 0; }

    for (int c0 = 0; c0 < NCODE; c0 += CCH) {
        float acc[4][4];
        #pragma unroll
        for (int i = 0; i < 4; ++i)
            #pragma unroll
            for (int j = 0; j < 4; ++j) acc[i][j] = 0.f;

        for (int d0 = 0; d0 < DIM; d0 += DCH) {
            __syncthreads();  // protect es from overwrite
            // stage e chunk: 128 codes x 64 floats = 2048 float4, 8/thread
            #pragma unroll
            for (int i = 0; i < 8; ++i) {
                int fi = t + 256 * i;
                int r  = fi >> 4;        // 0..127
                int c4 = fi & 15;        // 0..15
                float4 v = *(const float4*)(e + (size_t)(c0 + r) * DIM + d0 + (c4 << 2));
                *(float4*)(es + r * EPAD + (c4 << 2)) = v;
            }
            __syncthreads();

            #pragma unroll
            for (int q = 0; q < DCH / 4; ++q) {
                float4 xf[4], ef[4];
                #pragma unroll
                for (int i = 0; i < 4; ++i)
                    xf[i] = *(const float4*)(xs + ((rg << 2) + i) * DIM + d0 + (q << 2));
                #pragma unroll
                for (int j = 0; j < 4; ++j)
                    ef[j] = *(const float4*)(es + (cg + (j << 5)) * EPAD + (q << 2));
                #pragma unroll
                for (int i = 0; i < 4; ++i)
                    #pragma unroll
                    for (int j = 0; j < 4; ++j) {
                        acc[i][j] = fmaf(xf[i].x, ef[j].x, acc[i][j]);
                        acc[i][j] = fmaf(xf[i].y, ef[j].y, acc[i][j]);
                        acc[i][j] = fmaf(xf[i].z, ef[j].z, acc[i][j]);
                        acc[i][j] = fmaf(xf[i].w, ef[j].w, acc[i][j]);
                    }
            }
        }

        // epilogue: scores for this chunk, update running argmin
        #pragma unroll
        for (int j = 0; j < 4; ++j) {
            int c = c0 + cg + (j << 5);
            float sec = se[c];
            #pragma unroll
            for (int i = 0; i < 4; ++i) {
                float s = fmaf(-2.0f, acc[i][j], sec);
                if (s < best[i] || (s == best[i] && c < bi[i])) { best[i] = s; bi[i] = c; }
            }
        }
    }

    // reduce across the 32 lanes (cg) of each half-wave (rg constant per half)
    #pragma unroll
    for (int i = 0; i < 4; ++i) {
        float b = best[i]; int c = bi[i];
        #pragma unroll
        for (int m = 16; m >= 1; m >>= 1) {
            float ob = __shfl_xor(b, m, 64);
            int   oc = __shfl_xor(c, m, 64);
            if (ob < b || (ob == b && oc < c)) { b = ob; c = oc; }
        }
        if (cg == 0) idx_out[row0 + (rg << 2) + i] = c;
    }
}

// ---------------------------------------------------------------------------
// K2: gather + straight-through output + loss sum.
// out = x + (q - x) computed exactly as the reference (two fp32 roundings).
// loss accumulator: per-thread fp32 -> wave shfl -> block LDS -> f64 atomic.
// ---------------------------------------------------------------------------
__global__ __launch_bounds__(256)
void k_out_loss(const float* __restrict__ x, const float* __restrict__ e,
                const int* __restrict__ idx, float* __restrict__ out,
                double* __restrict__ sumsq) {
    const int T4 = OUT_ELEMS / 4;  // 4194304 float4
    int gid = blockIdx.x * blockDim.x + threadIdx.x;
    int stride = gridDim.x * blockDim.x;
    float local = 0.f;
    for (int f = gid; f < T4; f += stride) {
        int row = f >> 6;            // 64 float4 per row
        int col = f & 63;
        int k = idx[row];            // wave-uniform (64 consecutive f share a row)
        float4 xv = ((const float4*)x)[f];
        float4 qv = ((const float4*)(e + (size_t)k * DIM))[col];
        float4 d, o;
        d.x = qv.x - xv.x; d.y = qv.y - xv.y; d.z = qv.z - xv.z; d.w = qv.w - xv.w;
        o.x = xv.x + d.x;  o.y = xv.y + d.y;  o.z = xv.z + d.z;  o.w = xv.w + d.w;
        ((float4*)out)[f] = o;
        local += d.x * d.x + d.y * d.y + d.z * d.z + d.w * d.w;
    }
    #pragma unroll
    for (int m = 32; m >= 1; m >>= 1) local += __shfl_xor(local, m, 64);
    __shared__ float red[4];
    if ((threadIdx.x & 63) == 0) red[threadIdx.x >> 6] = local;
    __syncthreads();
    if (threadIdx.x == 0) {
        float s = red[0] + red[1] + red[2] + red[3];
        atomicAdd(sumsq, (double)s);
    }
}

// ---------------------------------------------------------------------------
// K3: histogram of indices
// ---------------------------------------------------------------------------
__global__ void k_hist(const int* __restrict__ idx, int* __restrict__ counts) {
    int i = blockIdx.x * blockDim.x + threadIdx.x;
    if (i < NROWS) atomicAdd(&counts[idx[i]], 1);
}

// ---------------------------------------------------------------------------
// K4: finalize loss + perplexity (single block)
// ---------------------------------------------------------------------------
__global__ __launch_bounds__(256)
void k_fin(const int* __restrict__ counts, const double* __restrict__ sumsq,
           float* __restrict__ out_scalars) {
    float local = 0.f;
    for (int c = threadIdx.x; c < NCODE; c += 256) {
        float p = (float)counts[c] * (1.0f / 65536.0f);
        local += p * logf(p + 1e-10f);
    }
    #pragma unroll
    for (int m = 32; m >= 1; m >>= 1) local += __shfl_xor(local, m, 64);
    __shared__ float red[4];
    if ((threadIdx.x & 63) == 0) red[threadIdx.x >> 6] = local;
    __syncthreads();
    if (threadIdx.x == 0) {
        float s = red[0] + red[1] + red[2] + red[3];
        float perp = expf(-s);
        float m = (float)(*sumsq * (1.0 / 16777216.0));
        float loss = m + 0.25f * m;   // q_latent + commitment*e_latent (equal values)
        out_scalars[0] = loss;
        out_scalars[1] = perp;
    }
}

// ---------------------------------------------------------------------------
extern "C" void kernel_launch(void* const* d_in, const int* in_sizes, int n_in,
                              void* d_out, int out_size, void* d_ws, size_t ws_size,
                              hipStream_t stream) {
    const float* x   = (const float*)d_in[0];   // [65536, 256]
    const float* emb = (const float*)d_in[1];   // [1024, 256]
    float* out = (float*)d_out;                 // [16777216 + 2]

    // workspace layout
    int*    idx    = (int*)d_ws;                            // 262144 B
    float*  se     = (float*)((char*)d_ws + 262144);        // 4096 B
    int*    counts = (int*)((char*)d_ws + 266240);          // 4096 B
    double* sumsq  = (double*)((char*)d_ws + 270336);       // 8 B

    hipMemsetAsync((char*)d_ws + 266240, 0, 4096 + 8, stream);

    k_se      <<<(NCODE + 255) / 256, 256, 0, stream>>>(emb, se);
    k_argmin  <<<NROWS / MT,          256, 0, stream>>>(x, emb, se, idx);
    k_out_loss<<<4096,                256, 0, stream>>>(x, emb, idx, out, sumsq);
    k_hist    <<<NROWS / 256,         256, 0, stream>>>(idx, counts);
    k_fin     <<<1,                   256, 0, stream>>>(counts, sumsq, out + OUT_ELEMS);
}

// Round 2
// 635.073 us; speedup vs baseline: 1.6064x; 1.6064x over previous
//
#include <hip/hip_runtime.h>
#include <hip/hip_bf16.h>

// Problem constants
#define NROWS 65536      // 64*32*32
#define DIM   256
#define NCODE 1024
#define OUT_ELEMS 16777216  // NROWS*DIM

// K1 tiling: 64 rows/block, 256-code chunks, 8-d chunks, 8x8 register tile
#define MT   64
#define CCH  256
#define DCH  8

// ---------------------------------------------------------------------------
// K0: per-code squared norms se[c] = sum_d e[c][d]^2
// ---------------------------------------------------------------------------
__global__ void k_se(const float* __restrict__ e, float* __restrict__ se) {
    int c = blockIdx.x * blockDim.x + threadIdx.x;
    if (c < NCODE) {
        const float4* r = (const float4*)(e + (size_t)c * DIM);
        float s = 0.f;
        #pragma unroll
        for (int i = 0; i < DIM / 4; ++i) {
            float4 v = r[i];
            s += v.x * v.x + v.y * v.y + v.z * v.z + v.w * v.w;
        }
        se[c] = s;
    }
}

// ---------------------------------------------------------------------------
// K1: fused distance + argmin.  score(n,k) = se[k] - 2*dot(x_n, e_k)
// Block 256 threads: rg = t>>5 (8 groups x 8 rows = 64 rows),
//                    cg = t&31 (32 lanes x 8 codes = 256-code chunk).
// xs: [64][256] f32 (64 KB), reads are half-wave broadcasts (2 addrs/wave).
// es: 256 codes x 8 d, stride 8 words, float4 position swizzled so one b128
//     read by 32 lanes hits all 8 bank-quads exactly 4x (hw minimum, no
//     conflict surcharge):  phys word = 8*c + 4*(q ^ ((c>>2)&1)), q = d>>2.
//     start bank = 8*(c&3) + 4*(q^((c>>2)&1)) -> 8 distinct quads x 4 lanes.
// ---------------------------------------------------------------------------
__global__ __launch_bounds__(256, 2)
void k_argmin(const float* __restrict__ x, const float* __restrict__ e,
              const float* __restrict__ se, int* __restrict__ idx_out) {
    __shared__ float xs[MT * DIM];      // 64 KB
    __shared__ float es[CCH * DCH];     // 8 KB, swizzled

    const int t  = threadIdx.x;
    const int rg = t >> 5;              // 0..7
    const int cg = t & 31;              // 0..31
    const int row0 = blockIdx.x * MT;

    // stage x tile: 16384 floats = 4096 float4, 16 per thread, coalesced
    {
        const float4* src = (const float4*)(x + (size_t)row0 * DIM);
        float4* dst = (float4*)xs;
        #pragma unroll
        for (int i = 0; i < 16; ++i) dst[t + 256 * i] = src[t + 256 * i];
    }

    float best[8];
    int   bi[8];
    #pragma unroll
    for (int i = 0; i < 8; ++i) { best[i] = 3.0e38f; bi[i] = 0; }

    for (int c0 = 0; c0 < NCODE; c0 += CCH) {
        float acc[8][8];
        #pragma unroll
        for (int i = 0; i < 8; ++i)
            #pragma unroll
            for (int j = 0; j < 8; ++j) acc[i][j] = 0.f;

        for (int d0 = 0; d0 < DIM; d0 += DCH) {
            __syncthreads();   // protect es (and xs on first iter) from readers
            // stage e chunk: 256 codes x 8 floats = 512 float4, 2 per thread
            #pragma unroll
            for (int i = 0; i < 2; ++i) {
                int fi = t + 256 * i;
                int c  = fi >> 1;          // 0..255
                int q  = fi & 1;           // 0..1
                float4 v = *(const float4*)(e + (size_t)(c0 + c) * DIM + d0 + (q << 2));
                int qp = q ^ ((c >> 2) & 1);
                *(float4*)(es + c * 8 + (qp << 2)) = v;
            }
            __syncthreads();

            #pragma unroll
            for (int q = 0; q < DCH / 4; ++q) {
                float4 xf[8], ef[8];
                #pragma unroll
                for (int i = 0; i < 8; ++i)
                    xf[i] = *(const float4*)(xs + (((rg << 3) + i) << 8) + d0 + (q << 2));
                #pragma unroll
                for (int j = 0; j < 8; ++j) {
                    int c  = cg + (j << 5);
                    int qp = q ^ ((c >> 2) & 1);
                    ef[j] = *(const float4*)(es + c * 8 + (qp << 2));
                }
                #pragma unroll
                for (int i = 0; i < 8; ++i)
                    #pragma unroll
                    for (int j = 0; j < 8; ++j) {
                        acc[i][j] = fmaf(xf[i].x, ef[j].x, acc[i][j]);
                        acc[i][j] = fmaf(xf[i].y, ef[j].y, acc[i][j]);
                        acc[i][j] = fmaf(xf[i].z, ef[j].z, acc[i][j]);
                        acc[i][j] = fmaf(xf[i].w, ef[j].w, acc[i][j]);
                    }
            }
        }

        // epilogue: scores for this chunk, update running argmin
        #pragma unroll
        for (int j = 0; j < 8; ++j) {
            int c = c0 + cg + (j << 5);
            float sec = se[c];
            #pragma unroll
            for (int i = 0; i < 8; ++i) {
                float s = fmaf(-2.0f, acc[i][j], sec);
                if (s < best[i] || (s == best[i] && c < bi[i])) { best[i] = s; bi[i] = c; }
            }
        }
    }

    // reduce across the 32 lanes (cg) of each half-wave (rg constant per half)
    #pragma unroll
    for (int i = 0; i < 8; ++i) {
        float b = best[i]; int c = bi[i];
        #pragma unroll
        for (int m = 16; m >= 1; m >>= 1) {
            float ob = __shfl_xor(b, m, 64);
            int   oc = __shfl_xor(c, m, 64);
            if (ob < b || (ob == b && oc < c)) { b = ob; c = oc; }
        }
        if (cg == 0) idx_out[row0 + (rg << 3) + i] = c;
    }
}

// ---------------------------------------------------------------------------
// K2: gather + straight-through output + loss sum.
// out = x + (q - x) computed exactly as the reference (two fp32 roundings).
// ---------------------------------------------------------------------------
__global__ __launch_bounds__(256)
void k_out_loss(const float* __restrict__ x, const float* __restrict__ e,
                const int* __restrict__ idx, float* __restrict__ out,
                double* __restrict__ sumsq) {
    const int T4 = OUT_ELEMS / 4;  // 4194304 float4
    int gid = blockIdx.x * blockDim.x + threadIdx.x;
    int stride = gridDim.x * blockDim.x;
    float local = 0.f;
    for (int f = gid; f < T4; f += stride) {
        int row = f >> 6;            // 64 float4 per row
        int col = f & 63;
        int k = idx[row];            // wave-uniform (64 consecutive f share a row)
        float4 xv = ((const float4*)x)[f];
        float4 qv = ((const float4*)(e + (size_t)k * DIM))[col];
        float4 d, o;
        d.x = qv.x - xv.x; d.y = qv.y - xv.y; d.z = qv.z - xv.z; d.w = qv.w - xv.w;
        o.x = xv.x + d.x;  o.y = xv.y + d.y;  o.z = xv.z + d.z;  o.w = xv.w + d.w;
        ((float4*)out)[f] = o;
        local += d.x * d.x + d.y * d.y + d.z * d.z + d.w * d.w;
    }
    #pragma unroll
    for (int m = 32; m >= 1; m >>= 1) local += __shfl_xor(local, m, 64);
    __shared__ float red[4];
    if ((threadIdx.x & 63) == 0) red[threadIdx.x >> 6] = local;
    __syncthreads();
    if (threadIdx.x == 0) {
        float s = red[0] + red[1] + red[2] + red[3];
        atomicAdd(sumsq, (double)s);
    }
}

// ---------------------------------------------------------------------------
// K3: histogram of indices
// ---------------------------------------------------------------------------
__global__ void k_hist(const int* __restrict__ idx, int* __restrict__ counts) {
    int i = blockIdx.x * blockDim.x + threadIdx.x;
    if (i < NROWS) atomicAdd(&counts[idx[i]], 1);
}

// ---------------------------------------------------------------------------
// K4: finalize loss + perplexity (single block)
// ---------------------------------------------------------------------------
__global__ __launch_bounds__(256)
void k_fin(const int* __restrict__ counts, const double* __restrict__ sumsq,
           float* __restrict__ out_scalars) {
    float local = 0.f;
    for (int c = threadIdx.x; c < NCODE; c += 256) {
        float p = (float)counts[c] * (1.0f / 65536.0f);
        local += p * logf(p + 1e-10f);
    }
    #pragma unroll
    for (int m = 32; m >= 1; m >>= 1) local += __shfl_xor(local, m, 64);
    __shared__ float red[4];
    if ((threadIdx.x & 63) == 0) red[threadIdx.x >> 6] = local;
    __syncthreads();
    if (threadIdx.x == 0) {
        float s = red[0] + red[1] + red[2] + red[3];
        float perp = expf(-s);
        float m = (float)(*sumsq * (1.0 / 16777216.0));
        float loss = m + 0.25f * m;   // q_latent + commitment*e_latent (equal values)
        out_scalars[0] = loss;
        out_scalars[1] = perp;
    }
}

// ---------------------------------------------------------------------------
extern "C" void kernel_launch(void* const* d_in, const int* in_sizes, int n_in,
                              void* d_out, int out_size, void* d_ws, size_t ws_size,
                              hipStream_t stream) {
    const float* x   = (const float*)d_in[0];   // [65536, 256]
    const float* emb = (const float*)d_in[1];   // [1024, 256]
    float* out = (float*)d_out;                 // [16777216 + 2]

    // workspace layout
    int*    idx    = (int*)d_ws;                            // 262144 B
    float*  se     = (float*)((char*)d_ws + 262144);        // 4096 B
    int*    counts = (int*)((char*)d_ws + 266240);          // 4096 B
    double* sumsq  = (double*)((char*)d_ws + 270336);       // 8 B

    hipMemsetAsync((char*)d_ws + 266240, 0, 4096 + 8, stream);

    k_se      <<<(NCODE + 255) / 256, 256, 0, stream>>>(emb, se);
    k_argmin  <<<NROWS / MT,          256, 0, stream>>>(x, emb, se, idx);
    k_out_loss<<<4096,                256, 0, stream>>>(x, emb, idx, out, sumsq);
    k_hist    <<<NROWS / 256,         256, 0, stream>>>(idx, counts);
    k_fin     <<<1,                   256, 0, stream>>>(counts, sumsq, out + OUT_ELEMS);
}

// Round 3
// 250.822 us; speedup vs baseline: 4.0672x; 2.5320x over previous
//
#include <hip/hip_runtime.h>
#include <hip/hip_bf16.h>

// Problem constants
#define NROWS 65536      // 64*32*32
#define DIM   256
#define NCODE 1024
#define OUT_ELEMS 16777216  // NROWS*DIM

typedef __attribute__((ext_vector_type(8))) short bf16x8;
typedef __attribute__((ext_vector_type(4))) float f32x4;

__device__ __forceinline__ unsigned umin_(unsigned a, unsigned b) { return a < b ? a : b; }

// RNE float->bf16 (finite inputs)
__device__ __forceinline__ unsigned short f2bf(float f) {
    unsigned b = __builtin_bit_cast(unsigned, f);
    return (unsigned short)((b + 0x7FFFu + ((b >> 16) & 1u)) >> 16);
}

// ---------------------------------------------------------------------------
// K0: per-code squared norms (+0.25 key offset folded in), fp32 exact
// ---------------------------------------------------------------------------
__global__ void k_se(const float* __restrict__ e, float* __restrict__ seb) {
    int c = blockIdx.x * blockDim.x + threadIdx.x;
    if (c < NCODE) {
        const float4* r = (const float4*)(e + (size_t)c * DIM);
        float s = 0.f;
        #pragma unroll
        for (int i = 0; i < DIM / 4; ++i) {
            float4 v = r[i];
            s += v.x * v.x + v.y * v.y + v.z * v.z + v.w * v.w;
        }
        seb[c] = s + 0.25f;
    }
}

// ---------------------------------------------------------------------------
// K0b: x fp32 -> bf16 row-major. 8 elems/thread.
// ---------------------------------------------------------------------------
__global__ __launch_bounds__(256)
void k_cvt_x(const float* __restrict__ x, unsigned short* __restrict__ xb) {
    int g = blockIdx.x * blockDim.x + threadIdx.x;   // 0 .. 2M-1
    const float4* src = (const float4*)x;
    float4 a = src[g * 2];
    float4 b = src[g * 2 + 1];
    bf16x8 o;
    o[0] = (short)f2bf(a.x); o[1] = (short)f2bf(a.y);
    o[2] = (short)f2bf(a.z); o[3] = (short)f2bf(a.w);
    o[4] = (short)f2bf(b.x); o[5] = (short)f2bf(b.y);
    o[6] = (short)f2bf(b.z); o[7] = (short)f2bf(b.w);
    *(bf16x8*)(xb + (size_t)g * 8) = o;
}

// ---------------------------------------------------------------------------
// K0c: codebook fp32 -> bf16 in MFMA B-fragment order.
// eb[((t*8+ks)*64 + lane)*8 + j] = e[n][k], n=t*16+(lane&15), k=ks*32+(lane>>4)*8+j
// ---------------------------------------------------------------------------
__global__ __launch_bounds__(256)
void k_cvt_e(const float* __restrict__ e, unsigned short* __restrict__ eb) {
    int g = blockIdx.x * blockDim.x + threadIdx.x;   // 0 .. 32767
    int lane = g & 63;
    int ks   = (g >> 6) & 7;
    int t    = g >> 9;
    int n  = t * 16 + (lane & 15);
    int k0 = ks * 32 + (lane >> 4) * 8;
    const float* src = e + (size_t)n * DIM + k0;
    bf16x8 o;
    #pragma unroll
    for (int j = 0; j < 8; ++j) o[j] = (short)f2bf(src[j]);
    *(bf16x8*)(eb + (size_t)g * 8) = o;
}

// ---------------------------------------------------------------------------
// K1: MFMA distance-argmin.  Block = 128 thr = 2 waves; 64 rows/block;
// wave w scans codes [w*512, w*512+512).  A (64 rows x 256 k, bf16) lives in
// registers: af[4 stripes][8 ksteps].  B frags streamed from pre-swizzled eb
// (fully coalesced 1 KB/instr, L2-resident).  16x16x32 MFMA:
//   A[m=lane&15][k=(lane>>4)*8+j], B[n=lane&15][k=(lane>>4)*8+j],
//   D col=lane&15, row=(lane>>4)*4+reg   (verified layouts, m89/m91).
// argmin via packed key: (bits(se+0.25-2dot) & ~1023) | code  -> min_u32.
// ---------------------------------------------------------------------------
__global__ __launch_bounds__(128, 2)
void k_argmin(const unsigned short* __restrict__ xb,
              const unsigned short* __restrict__ eb,
              const float* __restrict__ seb, int* __restrict__ idx_out) {
    const int t = threadIdx.x;
    const int w = t >> 6;            // wave 0/1
    const int l = t & 63;
    const int lr = l & 15;           // frag row/col index
    const int lh = l >> 4;           // quad
    const int row0 = blockIdx.x * 64;

    // A fragments: 4 stripes x 8 ksteps x 8 bf16 (128 VGPR)
    bf16x8 af[4][8];
    #pragma unroll
    for (int s = 0; s < 4; ++s) {
        const unsigned short* rp = xb + (size_t)(row0 + s * 16 + lr) * DIM + lh * 8;
        #pragma unroll
        for (int ks = 0; ks < 8; ++ks)
            af[s][ks] = *(const bf16x8*)(rp + ks * 32);
    }

    unsigned best[4][4];
    #pragma unroll
    for (int s = 0; s < 4; ++s)
        #pragma unroll
        for (int r = 0; r < 4; ++r) best[s][r] = 0xFFFFFFFFu;

    const int tile0 = w * 32;        // 32 16-code tiles per wave
    for (int tt = 0; tt < 32; ++tt) {
        const int ti = tile0 + tt;
        float se_l = seb[ti * 16 + lr];           // col for this lane
        const unsigned short* bp = eb + (size_t)ti * 4096 + (size_t)l * 8;
        bf16x8 bfr[8];
        #pragma unroll
        for (int ks = 0; ks < 8; ++ks)
            bfr[ks] = *(const bf16x8*)(bp + ks * 512);

        f32x4 acc[4];
        #pragma unroll
        for (int s = 0; s < 4; ++s) acc[s] = (f32x4){0.f, 0.f, 0.f, 0.f};
        #pragma unroll
        for (int ks = 0; ks < 8; ++ks)
            #pragma unroll
            for (int s = 0; s < 4; ++s)
                acc[s] = __builtin_amdgcn_mfma_f32_16x16x32_bf16(af[s][ks], bfr[ks], acc[s], 0, 0, 0);

        unsigned nlane = (unsigned)(ti * 16) | (unsigned)lr;
        #pragma unroll
        for (int s = 0; s < 4; ++s)
            #pragma unroll
            for (int r = 0; r < 4; ++r) {
                float sc = fmaf(-2.0f, acc[s][r], se_l);   // >0 by construction
                unsigned u = (__builtin_bit_cast(unsigned, sc) & 0xFFFFFC00u) | nlane;
                best[s][r] = umin_(best[s][r], u);
            }
    }

    // reduce over the 16 cols (lanes sharing lh): xor 1,2,4,8
    #pragma unroll
    for (int s = 0; s < 4; ++s)
        #pragma unroll
        for (int r = 0; r < 4; ++r) {
            unsigned b = best[s][r];
            #pragma unroll
            for (int m = 1; m <= 8; m <<= 1)
                b = umin_(b, (unsigned)__shfl_xor((int)b, m, 64));
            best[s][r] = b;
        }

    __shared__ unsigned keys[2][64];
    if (lr == 0) {
        #pragma unroll
        for (int s = 0; s < 4; ++s)
            #pragma unroll
            for (int r = 0; r < 4; ++r)
                keys[w][s * 16 + lh * 4 + r] = best[s][r];
    }
    __syncthreads();
    if (t < 64) {
        unsigned k2 = umin_(keys[0][t], keys[1][t]);
        idx_out[row0 + t] = (int)(k2 & 1023u);
    }
}

// ---------------------------------------------------------------------------
// K2: gather + straight-through output + loss sum (fp32 exact).
// ---------------------------------------------------------------------------
__global__ __launch_bounds__(256)
void k_out_loss(const float* __restrict__ x, const float* __restrict__ e,
                const int* __restrict__ idx, float* __restrict__ out,
                double* __restrict__ sumsq) {
    const int T4 = OUT_ELEMS / 4;
    int gid = blockIdx.x * blockDim.x + threadIdx.x;
    int stride = gridDim.x * blockDim.x;
    float local = 0.f;
    for (int f = gid; f < T4; f += stride) {
        int row = f >> 6;
        int col = f & 63;
        int k = idx[row];
        float4 xv = ((const float4*)x)[f];
        float4 qv = ((const float4*)(e + (size_t)k * DIM))[col];
        float4 d, o;
        d.x = qv.x - xv.x; d.y = qv.y - xv.y; d.z = qv.z - xv.z; d.w = qv.w - xv.w;
        o.x = xv.x + d.x;  o.y = xv.y + d.y;  o.z = xv.z + d.z;  o.w = xv.w + d.w;
        ((float4*)out)[f] = o;
        local += d.x * d.x + d.y * d.y + d.z * d.z + d.w * d.w;
    }
    #pragma unroll
    for (int m = 32; m >= 1; m >>= 1) local += __shfl_xor(local, m, 64);
    __shared__ float red[4];
    if ((threadIdx.x & 63) == 0) red[threadIdx.x >> 6] = local;
    __syncthreads();
    if (threadIdx.x == 0) {
        float s = red[0] + red[1] + red[2] + red[3];
        atomicAdd(sumsq, (double)s);
    }
}

// ---------------------------------------------------------------------------
// K3: histogram of indices
// ---------------------------------------------------------------------------
__global__ void k_hist(const int* __restrict__ idx, int* __restrict__ counts) {
    int i = blockIdx.x * blockDim.x + threadIdx.x;
    if (i < NROWS) atomicAdd(&counts[idx[i]], 1);
}

// ---------------------------------------------------------------------------
// K4: finalize loss + perplexity (single block)
// ---------------------------------------------------------------------------
__global__ __launch_bounds__(256)
void k_fin(const int* __restrict__ counts, const double* __restrict__ sumsq,
           float* __restrict__ out_scalars) {
    float local = 0.f;
    for (int c = threadIdx.x; c < NCODE; c += 256) {
        float p = (float)counts[c] * (1.0f / 65536.0f);
        local += p * logf(p + 1e-10f);
    }
    #pragma unroll
    for (int m = 32; m >= 1; m >>= 1) local += __shfl_xor(local, m, 64);
    __shared__ float red[4];
    if ((threadIdx.x & 63) == 0) red[threadIdx.x >> 6] = local;
    __syncthreads();
    if (threadIdx.x == 0) {
        float s = red[0] + red[1] + red[2] + red[3];
        float perp = expf(-s);
        float m = (float)(*sumsq * (1.0 / 16777216.0));
        float loss = m + 0.25f * m;
        out_scalars[0] = loss;
        out_scalars[1] = perp;
    }
}

// ---------------------------------------------------------------------------
extern "C" void kernel_launch(void* const* d_in, const int* in_sizes, int n_in,
                              void* d_out, int out_size, void* d_ws, size_t ws_size,
                              hipStream_t stream) {
    const float* x   = (const float*)d_in[0];   // [65536, 256]
    const float* emb = (const float*)d_in[1];   // [1024, 256]
    float* out = (float*)d_out;                 // [16777216 + 2]

    // small workspace (known-safe size from prior rounds)
    int*    idx    = (int*)d_ws;                            // 256 KB
    float*  seb    = (float*)((char*)d_ws + 262144);        // 4 KB
    int*    counts = (int*)((char*)d_ws + 266240);          // 4 KB
    double* sumsq  = (double*)((char*)d_ws + 270336);       // 8 B

    // big scratch lives in d_out: consumed by k_argmin BEFORE k_out_loss
    // overwrites d_out (stream-ordered). xb: 33.5 MB, eb: 512 KB << 67 MB.
    unsigned short* xb = (unsigned short*)d_out;                     // [65536*256] bf16
    unsigned short* eb = (unsigned short*)((char*)d_out + 33554432); // [262144] bf16

    hipMemsetAsync((char*)d_ws + 266240, 0, 4096 + 8, stream);

    k_se      <<<(NCODE + 255) / 256, 256, 0, stream>>>(emb, seb);
    k_cvt_x   <<<8192,                256, 0, stream>>>(x, xb);
    k_cvt_e   <<<128,                 256, 0, stream>>>(emb, eb);
    k_argmin  <<<NROWS / 64,          128, 0, stream>>>(xb, eb, seb, idx);
    k_out_loss<<<4096,                256, 0, stream>>>(x, emb, idx, out, sumsq);
    k_hist    <<<NROWS / 256,         256, 0, stream>>>(idx, counts);
    k_fin     <<<1,                   256, 0, stream>>>(counts, sumsq, out + OUT_ELEMS);
}

// Round 4
// 220.862 us; speedup vs baseline: 4.6190x; 1.1357x over previous
//
#include <hip/hip_runtime.h>
#include <hip/hip_bf16.h>

// Problem constants
#define NROWS 65536      // 64*32*32
#define DIM   256
#define NCODE 1024
#define OUT_ELEMS 16777216  // NROWS*DIM

typedef __attribute__((ext_vector_type(8))) short bf16x8;
typedef __attribute__((ext_vector_type(4))) float f32x4;

__device__ __forceinline__ unsigned umin_(unsigned a, unsigned b) { return a < b ? a : b; }

// RNE float->bf16 (finite inputs) — must stay bit-identical across rounds
__device__ __forceinline__ unsigned short f2bf(float f) {
    unsigned b = __builtin_bit_cast(unsigned, f);
    return (unsigned short)((b + 0x7FFFu + ((b >> 16) & 1u)) >> 16);
}

// ---------------------------------------------------------------------------
// K_prep: blocks 0..127: codebook fp32 -> bf16 in MFMA B-fragment order.
//   eb[((t*8+ks)*64 + lane)*8 + j] = e[n][k], n=t*16+(lane&15), k=ks*32+(lane>>4)*8+j
// blocks 128..131: per-code squared norms + 0.25 key offset (fp32 exact).
// ---------------------------------------------------------------------------
__global__ __launch_bounds__(256)
void k_prep(const float* __restrict__ e, float* __restrict__ seb,
            unsigned short* __restrict__ eb) {
    int b = blockIdx.x;
    if (b < 128) {
        int g = b * 256 + threadIdx.x;   // 0 .. 32767
        int lane = g & 63;
        int ks   = (g >> 6) & 7;
        int t    = g >> 9;
        int n  = t * 16 + (lane & 15);
        int k0 = ks * 32 + (lane >> 4) * 8;
        const float* src = e + (size_t)n * DIM + k0;
        bf16x8 o;
        #pragma unroll
        for (int j = 0; j < 8; ++j) o[j] = (short)f2bf(src[j]);
        *(bf16x8*)(eb + (size_t)g * 8) = o;
    } else {
        int c = (b - 128) * 256 + threadIdx.x;
        const float4* r = (const float4*)(e + (size_t)c * DIM);
        float s = 0.f;
        #pragma unroll
        for (int i = 0; i < DIM / 4; ++i) {
            float4 v = r[i];
            s += v.x * v.x + v.y * v.y + v.z * v.z + v.w * v.w;
        }
        seb[c] = s + 0.25f;
    }
}

// ---------------------------------------------------------------------------
// K1: MFMA distance-argmin.  Block = 256 thr = 4 waves; 128 rows/block.
// Wave w: row-group grp=w>>1 (64 rows), code-half half=w&1 (512 codes).
// A (64 rows x 256 k) converted fp32->bf16 in-register (each row touched by
// exactly one block -> conversion work equals the old k_cvt_x, traffic halved).
// B frags streamed from pre-swizzled eb (1 KB/instr, L2-resident).
// 16x16x32 MFMA layouts (verified m89/m91):
//   A[m=lane&15][k=(lane>>4)*8+j], B[n=lane&15][k=same], D col=lane&15,
//   row=(lane>>4)*4+reg.
// argmin via packed key: (bits(se+0.25-2dot) & ~1023) | code -> min_u32.
// Histogram fused into the epilogue.
// ---------------------------------------------------------------------------
__global__ __launch_bounds__(256, 2)
void k_argmin(const float* __restrict__ x,
              const unsigned short* __restrict__ eb,
              const float* __restrict__ seb,
              int* __restrict__ idx_out, int* __restrict__ counts) {
    const int t = threadIdx.x;
    const int w = t >> 6;            // wave 0..3
    const int l = t & 63;
    const int lr = l & 15;           // frag row/col index
    const int lh = l >> 4;           // quad
    const int grp  = w >> 1;         // row group 0/1
    const int half = w & 1;          // code half 0/1
    const int row0 = blockIdx.x * 128 + grp * 64;

    // A fragments: 4 stripes x 8 ksteps x 8 bf16 (128 VGPR), fp32 loads + cvt
    bf16x8 af[4][8];
    #pragma unroll
    for (int s = 0; s < 4; ++s) {
        const float* rp = x + (size_t)(row0 + s * 16 + lr) * DIM + lh * 8;
        #pragma unroll
        for (int ks = 0; ks < 8; ++ks) {
            float4 a = *(const float4*)(rp + ks * 32);
            float4 b = *(const float4*)(rp + ks * 32 + 4);
            bf16x8 o;
            o[0] = (short)f2bf(a.x); o[1] = (short)f2bf(a.y);
            o[2] = (short)f2bf(a.z); o[3] = (short)f2bf(a.w);
            o[4] = (short)f2bf(b.x); o[5] = (short)f2bf(b.y);
            o[6] = (short)f2bf(b.z); o[7] = (short)f2bf(b.w);
            af[s][ks] = o;
        }
    }

    unsigned best[4][4];
    #pragma unroll
    for (int s = 0; s < 4; ++s)
        #pragma unroll
        for (int r = 0; r < 4; ++r) best[s][r] = 0xFFFFFFFFu;

    const int tile0 = half * 32;     // 32 16-code tiles per wave
    for (int tt = 0; tt < 32; ++tt) {
        const int ti = tile0 + tt;
        float se_l = seb[ti * 16 + lr];           // col for this lane
        const unsigned short* bp = eb + (size_t)ti * 4096 + (size_t)l * 8;
        bf16x8 bfr[8];
        #pragma unroll
        for (int ks = 0; ks < 8; ++ks)
            bfr[ks] = *(const bf16x8*)(bp + ks * 512);

        f32x4 acc[4];
        #pragma unroll
        for (int s = 0; s < 4; ++s) acc[s] = (f32x4){0.f, 0.f, 0.f, 0.f};
        #pragma unroll
        for (int ks = 0; ks < 8; ++ks)
            #pragma unroll
            for (int s = 0; s < 4; ++s)
                acc[s] = __builtin_amdgcn_mfma_f32_16x16x32_bf16(af[s][ks], bfr[ks], acc[s], 0, 0, 0);

        unsigned nlane = (unsigned)(ti * 16) | (unsigned)lr;
        #pragma unroll
        for (int s = 0; s < 4; ++s)
            #pragma unroll
            for (int r = 0; r < 4; ++r) {
                float sc = fmaf(-2.0f, acc[s][r], se_l);   // >0 by construction
                unsigned u = (__builtin_bit_cast(unsigned, sc) & 0xFFFFFC00u) | nlane;
                best[s][r] = umin_(best[s][r], u);
            }
    }

    // reduce over the 16 cols (lanes sharing lh): xor 1,2,4,8
    #pragma unroll
    for (int s = 0; s < 4; ++s)
        #pragma unroll
        for (int r = 0; r < 4; ++r) {
            unsigned b = best[s][r];
            #pragma unroll
            for (int m = 1; m <= 8; m <<= 1)
                b = umin_(b, (unsigned)__shfl_xor((int)b, m, 64));
            best[s][r] = b;
        }

    __shared__ unsigned keys[4][64];
    if (lr == 0) {
        #pragma unroll
        for (int s = 0; s < 4; ++s)
            #pragma unroll
            for (int r = 0; r < 4; ++r)
                keys[w][s * 16 + lh * 4 + r] = best[s][r];
    }
    __syncthreads();
    if (t < 128) {
        int pair = t >> 6;           // row group
        int rr   = t & 63;
        unsigned k2 = umin_(keys[pair * 2][rr], keys[pair * 2 + 1][rr]);
        int code = (int)(k2 & 1023u);
        idx_out[blockIdx.x * 128 + pair * 64 + rr] = code;
        atomicAdd(&counts[code], 1);
    }
}

// ---------------------------------------------------------------------------
// K2: gather + straight-through output + loss sum (fp32 exact).
// Wave owns 8 rows; all idx loads, then all x loads, then all gathers are
// issued before any use -> ~16 KB in flight per wave (latency fix).
// ---------------------------------------------------------------------------
__global__ __launch_bounds__(256)
void k_out_loss(const float* __restrict__ x, const float* __restrict__ e,
                const int* __restrict__ idx, float* __restrict__ out,
                double* __restrict__ sumsq) {
    const int w = threadIdx.x >> 6;
    const int l = threadIdx.x & 63;
    const int row0 = blockIdx.x * 32 + w * 8;

    int k[8];
    #pragma unroll
    for (int r = 0; r < 8; ++r) k[r] = idx[row0 + r];
    float4 xv[8];
    #pragma unroll
    for (int r = 0; r < 8; ++r) xv[r] = ((const float4*)x)[(size_t)(row0 + r) * 64 + l];
    float4 qv[8];
    #pragma unroll
    for (int r = 0; r < 8; ++r) qv[r] = ((const float4*)e)[(size_t)k[r] * 64 + l];

    float local = 0.f;
    #pragma unroll
    for (int r = 0; r < 8; ++r) {
        float4 d, o;
        d.x = qv[r].x - xv[r].x; d.y = qv[r].y - xv[r].y;
        d.z = qv[r].z - xv[r].z; d.w = qv[r].w - xv[r].w;
        o.x = xv[r].x + d.x;  o.y = xv[r].y + d.y;
        o.z = xv[r].z + d.z;  o.w = xv[r].w + d.w;
        ((float4*)out)[(size_t)(row0 + r) * 64 + l] = o;
        local += d.x * d.x + d.y * d.y + d.z * d.z + d.w * d.w;
    }
    #pragma unroll
    for (int m = 32; m >= 1; m >>= 1) local += __shfl_xor(local, m, 64);
    __shared__ float red[4];
    if (l == 0) red[w] = local;
    __syncthreads();
    if (threadIdx.x == 0) {
        float s = red[0] + red[1] + red[2] + red[3];
        atomicAdd(sumsq, (double)s);
    }
}

// ---------------------------------------------------------------------------
// K4: finalize loss + perplexity (single block)
// ---------------------------------------------------------------------------
__global__ __launch_bounds__(256)
void k_fin(const int* __restrict__ counts, const double* __restrict__ sumsq,
           float* __restrict__ out_scalars) {
    float local = 0.f;
    for (int c = threadIdx.x; c < NCODE; c += 256) {
        float p = (float)counts[c] * (1.0f / 65536.0f);
        local += p * logf(p + 1e-10f);
    }
    #pragma unroll
    for (int m = 32; m >= 1; m >>= 1) local += __shfl_xor(local, m, 64);
    __shared__ float red[4];
    if ((threadIdx.x & 63) == 0) red[threadIdx.x >> 6] = local;
    __syncthreads();
    if (threadIdx.x == 0) {
        float s = red[0] + red[1] + red[2] + red[3];
        float perp = expf(-s);
        float m = (float)(*sumsq * (1.0 / 16777216.0));
        float loss = m + 0.25f * m;
        out_scalars[0] = loss;
        out_scalars[1] = perp;
    }
}

// ---------------------------------------------------------------------------
extern "C" void kernel_launch(void* const* d_in, const int* in_sizes, int n_in,
                              void* d_out, int out_size, void* d_ws, size_t ws_size,
                              hipStream_t stream) {
    const float* x   = (const float*)d_in[0];   // [65536, 256]
    const float* emb = (const float*)d_in[1];   // [1024, 256]
    float* out = (float*)d_out;                 // [16777216 + 2]

    // small workspace (known-safe size from prior rounds)
    int*    idx    = (int*)d_ws;                            // 256 KB
    float*  seb    = (float*)((char*)d_ws + 262144);        // 4 KB
    int*    counts = (int*)((char*)d_ws + 266240);          // 4 KB
    double* sumsq  = (double*)((char*)d_ws + 270336);       // 8 B

    // eb scratch lives in d_out: consumed by k_argmin BEFORE k_out_loss
    // overwrites d_out (stream-ordered).
    unsigned short* eb = (unsigned short*)((char*)d_out + 33554432); // 512 KB

    hipMemsetAsync((char*)d_ws + 266240, 0, 4096 + 8, stream);

    k_prep    <<<132,        256, 0, stream>>>(emb, seb, eb);
    k_argmin  <<<NROWS / 128, 256, 0, stream>>>(x, eb, seb, idx, counts);
    k_out_loss<<<NROWS / 32,  256, 0, stream>>>(x, emb, idx, out, sumsq);
    k_fin     <<<1,          256, 0, stream>>>(counts, sumsq, out + OUT_ELEMS);
}